// Round 1
// baseline (232.911 us; speedup 1.0000x reference)
//
#include <hip/hip_runtime.h>
#include <hip/hip_bf16.h>

#define NROWS 8192
#define DIM   512
#define KSEL  20
#define PANEL 1024
#define NSURV 512

typedef unsigned int u32;
typedef unsigned long long u64;
typedef short bf16x8 __attribute__((ext_vector_type(8)));
typedef float f32x4 __attribute__((ext_vector_type(4)));
typedef ushort u16x2 __attribute__((ext_vector_type(2)));

typedef const void __attribute__((address_space(1))) as1_void;
typedef void __attribute__((address_space(3))) as3_void;

__device__ __forceinline__ void async_ld16(const ushort* g, ushort* l) {
    __builtin_amdgcn_global_load_lds((as1_void*)g, (as3_void*)l, 16, 0, 0);
}

// round-to-nearest-even f32 -> bf16 bits
__device__ __forceinline__ ushort f2bf(float f) {
    u32 u = __float_as_uint(f);
    return (ushort)((u + 0x7FFFu + ((u >> 16) & 1u)) >> 16);
}

// monotone map for one u16 bf16 pattern: integer compare == float compare
__device__ __forceinline__ u32 mono16(u32 r) {
    return r ^ (0x8000u | ((r >> 15) * 0x7FFFu));
}

__device__ __forceinline__ u32 mkey(float f) { return mono16((u32)f2bf(f)); }

// packed u16x2 max
__device__ __forceinline__ u32 pkmax(u32 a, u32 b) {
    union { u32 u; u16x2 v; } x, y; x.u = a; y.u = b;
    x.v = __builtin_elementwise_max(x.v, y.v);
    return x.u;
}

// ---------------- normalize: fp32 rows -> unit-norm bf16 rows ----------------
__global__ __launch_bounds__(256) void k_norm(const float* __restrict__ x,
                                              ushort* __restrict__ xn) {
    int lane = threadIdx.x & 63;
    int wv   = threadIdx.x >> 6;
    int row  = blockIdx.x * 4 + wv;
    const float4* xr = (const float4*)(x + (size_t)row * DIM);
    float4 a = xr[2 * lane];
    float4 b = xr[2 * lane + 1];
    float ss = a.x*a.x + a.y*a.y + a.z*a.z + a.w*a.w
             + b.x*b.x + b.y*b.y + b.z*b.z + b.w*b.w;
    #pragma unroll
    for (int off = 32; off; off >>= 1) ss += __shfl_xor(ss, off);
    float sc = 1.0f / fmaxf(sqrtf(ss), 1e-12f);
    float v[8] = {a.x*sc, a.y*sc, a.z*sc, a.w*sc, b.x*sc, b.y*sc, b.z*sc, b.w*sc};
    union { ushort u[8]; uint4 q; } o;
    #pragma unroll
    for (int i = 0; i < 8; ++i) o.u[i] = f2bf(v[i]);
    *(uint4*)(xn + (size_t)row * DIM + lane * 8) = o.q;
}

// ---------------- GEMM: C = Xn * Xn^T (bf16 out), diag = -3.0 ----------------
// 128x128 tile, 4 waves (2x2), each wave 4x4 subtiles of 16x16x32 bf16 MFMA.
// TRI=true: 2080 lower-triangle blocks (bx<=by), XCD-bijective swizzled so
// each XCD owns a contiguous triangle range (A-panel stays hot in its L2).
// Epilogue is fully register-resident with direct NONTEMPORAL stores (no LDS
// re-stage, no extra barriers, no RFO fetch):
//   mirror tile: p01=h0|h1<<16, p23=h2|h3<<16 are row-pairs of C^T -> one
//     dwordx2 per (i,j); per instr: 16 rows x 32B contiguous.
//   row tile: shfl_xor(1) + v_perm packs neighbor-lane col-pairs; even lanes
//     emit rows r0/r1, odd lanes r2/r3 -> 2 b32 stores per (i,j); per instr:
//     8 rows x 32B contiguous. L2 merges adjacent 32B halves into full lines.
template<bool TRI>
__global__ __launch_bounds__(256) void k_gemm(const ushort* __restrict__ xn,
                                              ushort* __restrict__ C,
                                              ushort* __restrict__ M,
                                              int row0) {
    __shared__ ushort sh[128 * 128];         // K-loop A|B staging only
    ushort* lA = sh;
    ushort* lB = sh + 128 * 64;
    int tid  = threadIdx.x;
    int lane = tid & 63, wv = tid >> 6;
    int wr = wv >> 1, wc = wv & 1;
    int q = lane >> 4, m = lane & 15;
    int bx, by;
    if (TRI) {
        int t = (int)blockIdx.x;
        t = (t & 7) * 260 + (t >> 3);        // XCD swizzle: 2080 = 8 * 260 (bijective)
        by = (int)((sqrtf(8.0f * (float)t + 1.0f) - 1.0f) * 0.5f);
        while ((by + 1) * (by + 2) / 2 <= t) ++by;
        while (by * (by + 1) / 2 > t) --by;
        bx = t - by * (by + 1) / 2;          // bx <= by
    } else {
        bx = blockIdx.x; by = blockIdx.y;
    }
    int grow0 = row0 + by * 128;   // A rows (global)
    int gcol0 = bx * 128;          // B rows = C cols (global)
    f32x4 acc[4][4] = {};

    int lr = lane >> 3;   // row within 8-row group
    int lc = lane & 7;    // LDS chunk slot this lane fills
    for (int kc = 0; kc < 8; ++kc) {
        #pragma unroll
        for (int t = 0; t < 4; ++t) {
            int rb  = wv * 32 + t * 8;     // wave-uniform row base
            int r   = rb + lr;
            int fch = lc ^ (r & 7);        // XOR chunk swizzle (bank-conflict-free)
            async_ld16(xn + (size_t)(grow0 + r) * DIM + kc * 64 + fch * 8, &lA[rb * 64]);
            async_ld16(xn + (size_t)(gcol0 + r) * DIM + kc * 64 + fch * 8, &lB[rb * 64]);
        }
        __syncthreads();
        #pragma unroll
        for (int s = 0; s < 2; ++s) {
            bf16x8 af[4], bfr[4];
            #pragma unroll
            for (int i = 0; i < 4; ++i) {
                int ra = wr * 64 + i * 16 + m;
                af[i]  = *(const bf16x8*)&lA[ra * 64 + (((s * 4 + q) ^ (ra & 7)) * 8)];
                int rb2 = wc * 64 + i * 16 + m;
                bfr[i] = *(const bf16x8*)&lB[rb2 * 64 + (((s * 4 + q) ^ (rb2 & 7)) * 8)];
            }
            #pragma unroll
            for (int i = 0; i < 4; ++i)
                #pragma unroll
                for (int j = 0; j < 4; ++j)
                    acc[i][j] = __builtin_amdgcn_mfma_f32_16x16x32_bf16(af[i], bfr[j], acc[i][j], 0, 0, 0);
        }
        __syncthreads();
    }

    // ---- epilogue: all-register, direct nontemporal stores + M digest ----
    // C/D layout: col=lane&15, row=quad*4+reg (m89/m91-verified)
    bool isdiag = (row0 + by * 128) == gcol0;   // only block that contains diag
    u32* Cw = (u32*)C;
    const int NW = NROWS / 2;                    // row stride in dwords
    float cmf[4] = {-3.0f, -3.0f, -3.0f, -3.0f};     // per-j col maxima
    #pragma unroll
    for (int i = 0; i < 4; ++i) {
        float rmf[4] = {-3.0f, -3.0f, -3.0f, -3.0f}; // per-reg row maxima
        int rloc = wr * 64 + i * 16 + q * 4;         // local row base (0..127)
        #pragma unroll
        for (int j = 0; j < 4; ++j) {
            int cl = wc * 64 + j * 16 + m;           // local col
            int c  = gcol0 + cl;                     // global col
            ushort h[4];
            #pragma unroll
            for (int reg = 0; reg < 4; ++reg) {
                float a  = acc[i][j][reg];
                ushort hb = f2bf(a);
                float mv = a;
                if (isdiag && (row0 + by * 128 + rloc + reg) == c) {
                    hb = (ushort)0xC040;             // bf16(-3.0)
                    mv = -3.0f;
                }
                h[reg]   = hb;
                rmf[reg] = fmaxf(rmf[reg], mv);
                cmf[j]   = fmaxf(cmf[j], mv);
            }
            // pack row-pairs once; reused for both tiles
            u32 p01 = (u32)h[0] | ((u32)h[1] << 16);
            u32 p23 = (u32)h[2] | ((u32)h[3] << 16);

            if (TRI && bx != by) {
                // mirror: C^T row = orig col, cols rloc..rloc+3 contiguous (8B)
                u64 pk = (u64)p01 | ((u64)p23 << 32);
                size_t off = (size_t)(gcol0 + cl) * NW + (u32)((by * 128 + rloc) >> 1);
                __builtin_nontemporal_store(pk, (u64*)(Cw + off));
            }

            // row tile: pair neighbor-lane cols via shfl_xor(1) + v_perm
            u32 x01 = (u32)__shfl_xor((int)p01, 1);
            u32 x23 = (u32)__shfl_xor((int)p23, 1);
            bool odd = (m & 1) != 0;
            u32 hi = odd ? p23 : x01;       // even lane: nbr p01 ; odd: own p23
            u32 lo = odd ? x23 : p01;       // even lane: own p01 ; odd: nbr p23
            u32 dA = __builtin_amdgcn_perm(hi, lo, 0x05040100u); // lo.lo16 | hi.lo16<<16
            u32 dB = __builtin_amdgcn_perm(hi, lo, 0x07060302u); // lo.hi16 | hi.hi16<<16
            int rA = rloc + (odd ? 2 : 0);  // even lanes rows r0/r1, odd r2/r3
            size_t cwo = (size_t)(by * 128 + rA) * NW
                       + (u32)((gcol0 >> 1) + wc * 32 + j * 8 + (m >> 1));
            __builtin_nontemporal_store(dA, Cw + cwo);        // row rA
            __builtin_nontemporal_store(dB, Cw + cwo + NW);   // row rA+1
        }
        // row maxima: packed 2-rows/u32, reduce over 16 lanes (m) of each quad
        u32 kp01 = mkey(rmf[0]) | (mkey(rmf[1]) << 16);
        u32 kp23 = mkey(rmf[2]) | (mkey(rmf[3]) << 16);
        #pragma unroll
        for (int off = 1; off <= 8; off <<= 1) {
            kp01 = pkmax(kp01, (u32)__shfl_xor((int)kp01, off));
            kp23 = pkmax(kp23, (u32)__shfl_xor((int)kp23, off));
        }
        if (m == 0) {
            size_t mb = (size_t)(row0 + by * 128 + rloc) * 128 + bx * 2 + wc;
            M[mb]       = (ushort)(kp01 & 0xFFFFu);
            M[mb + 128] = (ushort)(kp01 >> 16);
            M[mb + 256] = (ushort)(kp23 & 0xFFFFu);
            M[mb + 384] = (ushort)(kp23 >> 16);
        }
    }
    if (TRI && bx != by) {
        // col maxima (mirror rows): packed 2-cols/u32, reduce over quads (q)
        u32 q01 = mkey(cmf[0]) | (mkey(cmf[1]) << 16);
        u32 q23 = mkey(cmf[2]) | (mkey(cmf[3]) << 16);
        q01 = pkmax(q01, (u32)__shfl_xor((int)q01, 16));
        q01 = pkmax(q01, (u32)__shfl_xor((int)q01, 32));
        q23 = pkmax(q23, (u32)__shfl_xor((int)q23, 16));
        q23 = pkmax(q23, (u32)__shfl_xor((int)q23, 32));
        if (q == 0) {
            int gc = gcol0 + wc * 64 + m;
            int sg = by * 2 + wr;
            M[(size_t)(gc +  0) * 128 + sg] = (ushort)(q01 & 0xFFFFu);
            M[(size_t)(gc + 16) * 128 + sg] = (ushort)(q01 >> 16);
            M[(size_t)(gc + 32) * 128 + sg] = (ushort)(q23 & 0xFFFFu);
            M[(size_t)(gc + 48) * 128 + sg] = (ushort)(q23 >> 16);
        }
    }
}

// ---------------- select: ballot-bsearch top-20 + BCE ------------------------
__global__ __launch_bounds__(256) void k_select(const ushort* __restrict__ C,
                                                const ushort* __restrict__ M,
                                                const int* __restrict__ labels,
                                                int row0,
                                                float* __restrict__ partials) {
    __shared__ u32 s_surv[4][NSURV];
    __shared__ u32 s_seg[4][128];
    __shared__ u32 s_cnt[4];
    __shared__ u32 s_scnt[4];
    int lane = threadIdx.x & 63;
    int wv   = threadIdx.x >> 6;
    int prow = blockIdx.x * 4 + wv;
    int grow = row0 + prow;
    const ushort* rowC = C + (size_t)prow * NROWS;

    if (lane == 0) { s_cnt[wv] = 0; s_scnt[wv] = 0; }
    __syncthreads();

    // segment maxima (mono keys): lane holds segs 2*lane, 2*lane+1
    u32 pm  = *(const u32*)&M[(size_t)grow * 128 + 2 * lane];
    u32 klo = pm & 0xFFFFu, khi = pm >> 16;

    // T = largest 16-bit value with count(seg_max >= T) >= KSEL
    u32 T = 0;
    #pragma unroll
    for (int b = 15; b >= 0; --b) {
        u32 cand = T | (1u << b);
        int c = __popcll(__ballot(klo >= cand)) + __popcll(__ballot(khi >= cand));
        if (c >= KSEL) T = cand;
    }

    // survivor-segment id list in LDS (replaces serial ctz chain)
    if (klo >= T) { u32 p = atomicAdd(&s_scnt[wv], 1u); s_seg[wv][p] = 2u * lane; }
    if (khi >= T) { u32 p = atomicAdd(&s_scnt[wv], 1u); s_seg[wv][p] = 2u * lane + 1u; }
    u32 nseg = s_scnt[wv];
    int grp = lane >> 3, sub = lane & 7;   // 8 lanes per segment

    // fast path: up to 32 segments as 4 independent uint4 loads (one mem epoch)
    int  sid[4];
    uint4 vv[4];
    #pragma unroll
    for (int t = 0; t < 4; ++t) {
        u32 ix = (u32)(t * 8 + grp);
        sid[t] = (ix < nseg) ? (int)s_seg[wv][ix] : -1;
    }
    #pragma unroll
    for (int t = 0; t < 4; ++t) {
        if (sid[t] >= 0) vv[t] = *(const uint4*)(rowC + sid[t] * 64 + sub * 8);
    }
    #pragma unroll
    for (int t = 0; t < 4; ++t) {
        if (sid[t] < 0) continue;
        u32 wds[4] = { vv[t].x, vv[t].y, vv[t].z, vv[t].w };
        u32 cbase = (u32)(sid[t] * 64 + sub * 8);
        #pragma unroll
        for (int h = 0; h < 4; ++h) {
            u32 w  = wds[h];
            u32 kA = mono16(w & 0xFFFFu);
            u32 kB = mono16(w >> 16);
            if (kA >= T) { u32 p = atomicAdd(&s_cnt[wv], 1u); if (p < NSURV) s_surv[wv][p] = (kA << 16) | (cbase + 2u * h); }
            if (kB >= T) { u32 p = atomicAdd(&s_cnt[wv], 1u); if (p < NSURV) s_surv[wv][p] = (kB << 16) | (cbase + 2u * h + 1u); }
        }
    }
    // rare tail: nseg > 32
    for (u32 base = 32; base < nseg; base += 8) {
        u32 ix = base + (u32)grp;
        if (ix >= nseg) continue;
        int s = (int)s_seg[wv][ix];
        uint4 v = *(const uint4*)(rowC + s * 64 + sub * 8);
        u32 wds[4] = { v.x, v.y, v.z, v.w };
        u32 cbase = (u32)(s * 64 + sub * 8);
        #pragma unroll
        for (int h = 0; h < 4; ++h) {
            u32 w  = wds[h];
            u32 kA = mono16(w & 0xFFFFu);
            u32 kB = mono16(w >> 16);
            if (kA >= T) { u32 p = atomicAdd(&s_cnt[wv], 1u); if (p < NSURV) s_surv[wv][p] = (kA << 16) | (cbase + 2u * h); }
            if (kB >= T) { u32 p = atomicAdd(&s_cnt[wv], 1u); if (p < NSURV) s_surv[wv][p] = (kB << 16) | (cbase + 2u * h + 1u); }
        }
    }

    u32 cnt = min(s_cnt[wv], (u32)NSURV);     // same-wave LDS: ordered
    int mylab = labels[grow];
    float loss = 0.0f;

    if (cnt <= 64u) {
        // fast path: one survivor per lane; V20 bsearch = 16 ballots
        u32 gg  = ((u32)lane < cnt) ? s_surv[wv][lane] : 0u;
        u32 key = gg >> 16;
        u32 V = 0;
        #pragma unroll
        for (int b = 15; b >= 0; --b) {
            u32 cand = V | (1u << b);
            if (__popcll(__ballot(key >= cand)) >= KSEL) V = cand;
        }
        int cgt  = __popcll(__ballot(key > V));
        int ceq  = __popcll(__ballot(gg != 0 && key == V));
        int need = KSEL - cgt;
        bool incl;
        if (ceq == need) {
            incl = (gg != 0) && (key >= V);
        } else {
            // more ties than slots: take `need` largest cols among ties
            u32 col = gg & 0xFFFFu;
            bool tie = (gg != 0) && (key == V);
            u32 Cv = 0;
            #pragma unroll
            for (int b = 15; b >= 0; --b) {
                u32 cand2 = Cv | (1u << b);
                if (__popcll(__ballot(tie && col >= cand2)) >= need) Cv = cand2;
            }
            incl = (key > V) || (tie && col >= Cv);   // cols unique -> exact
        }
        if (incl) {
            u32 col = gg & 0xFFFFu;
            u32 raw = (key & 0x8000u) ? (key ^ 0x8000u) : (key ^ 0xFFFFu);
            float v = __uint_as_float(raw << 16);
            float p = (v + 1.0f) * 0.5f;
            bool tm = (labels[col] == mylab);
            loss -= tm ? fmaxf(logf(p), -100.0f) : fmaxf(log1pf(-p), -100.0f);
        }
    } else {
        // fallback (rare): 8 survivors per lane
        u32 g[8];
        #pragma unroll
        for (int j = 0; j < 8; ++j) {
            u32 idx = (u32)lane + (u32)j * 64u;
            g[j] = (idx < cnt) ? s_surv[wv][idx] : 0u;
        }
        u32 V = 0;
        #pragma unroll
        for (int b = 15; b >= 0; --b) {
            u32 cand = V | (1u << b);
            int c = 0;
            #pragma unroll
            for (int j = 0; j < 8; ++j)
                c += __popcll(__ballot((g[j] >> 16) >= cand));
            if (c >= KSEL) V = cand;
        }
        int cgt = 0, ceq = 0;
        #pragma unroll
        for (int j = 0; j < 8; ++j) {
            cgt += __popcll(__ballot(g[j] != 0 && (g[j] >> 16) > V));
            ceq += __popcll(__ballot(g[j] != 0 && (g[j] >> 16) == V));
        }
        int need = KSEL - cgt;
        bool all_ties = (ceq == need);
        #pragma unroll
        for (int j = 0; j < 8; ++j) {
            u32 key = g[j] >> 16, col = g[j] & 0xFFFFu;
            if (g[j] != 0 && (key > V || (all_ties && key == V))) {
                u32 raw = (key & 0x8000u) ? (key ^ 0x8000u) : (key ^ 0xFFFFu);
                float v = __uint_as_float(raw << 16);
                float p = (v + 1.0f) * 0.5f;
                bool tm = (labels[col] == mylab);
                loss -= tm ? fmaxf(logf(p), -100.0f) : fmaxf(log1pf(-p), -100.0f);
            }
        }
        if (!all_ties) {
            for (int r = 0; r < need; ++r) {
                u32 best = 0;
                #pragma unroll
                for (int j = 0; j < 8; ++j) {
                    u32 c2 = (g[j] != 0 && (g[j] >> 16) == V) ? ((g[j] & 0xFFFFu) + 1u) : 0u;
                    best = max(best, c2);
                }
                #pragma unroll
                for (int off = 32; off; off >>= 1) best = max(best, (u32)__shfl_xor((int)best, off));
                #pragma unroll
                for (int j = 0; j < 8; ++j) {
                    if (g[j] != 0 && (g[j] >> 16) == V && ((g[j] & 0xFFFFu) + 1u) == best) {
                        u32 col = g[j] & 0xFFFFu;
                        u32 raw = (V & 0x8000u) ? (V ^ 0x8000u) : (V ^ 0xFFFFu);
                        float v = __uint_as_float(raw << 16);
                        float p = (v + 1.0f) * 0.5f;
                        bool tm = (labels[col] == mylab);
                        loss -= tm ? fmaxf(logf(p), -100.0f) : fmaxf(log1pf(-p), -100.0f);
                        g[j] = 0;
                    }
                }
            }
        }
    }

    #pragma unroll
    for (int off = 32; off; off >>= 1) loss += __shfl_xor(loss, off);
    if (lane == 0) partials[grow] = loss;
}

__global__ __launch_bounds__(256) void k_final(const float* __restrict__ partials,
                                               float* __restrict__ out) {
    __shared__ float s[4];
    int tid = threadIdx.x, lane = tid & 63, wvi = tid >> 6;
    const float4* p4 = (const float4*)partials;
    float sum = 0.0f;
    #pragma unroll
    for (int i = 0; i < 8; ++i) {
        float4 v = p4[tid + i * 256];
        sum += v.x + v.y + v.z + v.w;
    }
    #pragma unroll
    for (int off = 32; off; off >>= 1) sum += __shfl_xor(sum, off);
    if (lane == 0) s[wvi] = sum;
    __syncthreads();
    if (tid == 0) out[0] = (s[0] + s[1] + s[2] + s[3]) * (1.0f / (float)(NROWS * KSEL));
}

extern "C" void kernel_launch(void* const* d_in, const int* in_sizes, int n_in,
                              void* d_out, int out_size, void* d_ws, size_t ws_size,
                              hipStream_t stream) {
    const float* batch  = (const float*)d_in[0];
    const int*   labels = (const int*)d_in[1];

    ushort* xn = (ushort*)d_ws;
    ushort* C  = xn + (size_t)NROWS * DIM;
    // M (2 MB) and partials (32 KB) live in the batch input buffer (16 MB):
    // batch is fully consumed by k_norm before k_gemm/k_select write them.
    ushort* M        = (ushort*)d_in[0];
    float*  partials = (float*)((char*)d_in[0] + (4u << 20));

    size_t need_full = (size_t)NROWS * DIM * 2 + (size_t)NROWS * NROWS * 2;

    k_norm<<<NROWS / 4, 256, 0, stream>>>(batch, xn);

    if (ws_size >= need_full) {
        // full symmetric path: 2080 lower-triangle blocks, one select pass
        k_gemm<true><<<dim3(64 * 65 / 2), 256, 0, stream>>>(xn, C, M, 0);
        k_select<<<NROWS / 4, 256, 0, stream>>>(C, M, labels, 0, partials);
    } else {
        // fallback: panel path (24 MB of ws)
        for (int p = 0; p < NROWS / PANEL; ++p) {
            k_gemm<false><<<dim3(64, PANEL / 128), 256, 0, stream>>>(xn, C, M, p * PANEL);
            k_select<<<PANEL / 4, 256, 0, stream>>>(C, M, labels, p * PANEL, partials);
        }
    }
    k_final<<<1, 256, 0, stream>>>(partials, (float*)d_out);
}

// Round 2
// 205.934 us; speedup vs baseline: 1.1310x; 1.1310x over previous
//
#include <hip/hip_runtime.h>
#include <hip/hip_bf16.h>

#define NROWS 8192
#define DIM   512
#define KSEL  20
#define PANEL 1024
#define NSURV 512

typedef unsigned int u32;
typedef unsigned long long u64;
typedef short bf16x8 __attribute__((ext_vector_type(8)));
typedef float f32x4 __attribute__((ext_vector_type(4)));
typedef ushort u16x2 __attribute__((ext_vector_type(2)));

typedef const void __attribute__((address_space(1))) as1_void;
typedef void __attribute__((address_space(3))) as3_void;

__device__ __forceinline__ void async_ld16(const ushort* g, ushort* l) {
    __builtin_amdgcn_global_load_lds((as1_void*)g, (as3_void*)l, 16, 0, 0);
}

// round-to-nearest-even f32 -> bf16 bits
__device__ __forceinline__ ushort f2bf(float f) {
    u32 u = __float_as_uint(f);
    return (ushort)((u + 0x7FFFu + ((u >> 16) & 1u)) >> 16);
}

// monotone map for one u16 bf16 pattern: integer compare == float compare
__device__ __forceinline__ u32 mono16(u32 r) {
    return r ^ (0x8000u | ((r >> 15) * 0x7FFFu));
}

__device__ __forceinline__ u32 mkey(float f) { return mono16((u32)f2bf(f)); }

// packed u16x2 max
__device__ __forceinline__ u32 pkmax(u32 a, u32 b) {
    union { u32 u; u16x2 v; } x, y; x.u = a; y.u = b;
    x.v = __builtin_elementwise_max(x.v, y.v);
    return x.u;
}

// ---------------- normalize: fp32 rows -> unit-norm bf16 rows ----------------
__global__ __launch_bounds__(256) void k_norm(const float* __restrict__ x,
                                              ushort* __restrict__ xn) {
    int lane = threadIdx.x & 63;
    int wv   = threadIdx.x >> 6;
    int row  = blockIdx.x * 4 + wv;
    const float4* xr = (const float4*)(x + (size_t)row * DIM);
    float4 a = xr[2 * lane];
    float4 b = xr[2 * lane + 1];
    float ss = a.x*a.x + a.y*a.y + a.z*a.z + a.w*a.w
             + b.x*b.x + b.y*b.y + b.z*b.z + b.w*b.w;
    #pragma unroll
    for (int off = 32; off; off >>= 1) ss += __shfl_xor(ss, off);
    float sc = 1.0f / fmaxf(sqrtf(ss), 1e-12f);
    float v[8] = {a.x*sc, a.y*sc, a.z*sc, a.w*sc, b.x*sc, b.y*sc, b.z*sc, b.w*sc};
    union { ushort u[8]; uint4 q; } o;
    #pragma unroll
    for (int i = 0; i < 8; ++i) o.u[i] = f2bf(v[i]);
    *(uint4*)(xn + (size_t)row * DIM + lane * 8) = o.q;
}

// ---------------- GEMM: C = Xn * Xn^T (bf16 out), diag = -3.0 ----------------
// 256x256 tile, 512 threads = 8 waves (2 wave-rows x 4 wave-cols), each wave a
// 128x64 output (8x4 subtiles of 16x16x32 bf16 MFMA). Same proven schedule as
// the 128^2 version (stage -> barrier -> MFMA -> barrier, 8 K-steps) but with
// 2x MFMA per barrier per wave, half the logical panel fetch, and half the
// per-output epilogue overhead (528 triangle blocks instead of 2080).
// Epilogue: row tile staged via LDS in two 64KB halves (dword-XOR swizzle,
// conflict-free scalar writes, coalesced b128 readback/store). Mirror tile via
// direct TEMPORAL u64 stores (16 rows x 32B runs per instr; L2 merges lines —
// round-1 showed the write-amp came from the nontemporal flag, now removed).
template<bool TRI>
__global__ __launch_bounds__(512, 2) void k_gemm(const ushort* __restrict__ xn,
                                                 ushort* __restrict__ C,
                                                 ushort* __restrict__ M,
                                                 int row0) {
    __shared__ ushort sh[2 * 256 * 64];      // 64 KB: K-loop A|B; epi: half-tile
    ushort* lA = sh;
    ushort* lB = sh + 256 * 64;
    int tid  = threadIdx.x;
    int lane = tid & 63, wv = tid >> 6;       // wv 0..7
    int wr = wv >> 2, wc = wv & 3;            // 2 x 4 wave grid
    int q = lane >> 4, m = lane & 15;
    int bx, by;
    if (TRI) {
        int t = (int)blockIdx.x;
        t = (t & 7) * 66 + (t >> 3);          // XCD swizzle: 528 = 8*66 (bijective)
        by = (int)((sqrtf(8.0f * (float)t + 1.0f) - 1.0f) * 0.5f);
        while ((by + 1) * (by + 2) / 2 <= t) ++by;
        while (by * (by + 1) / 2 > t) --by;
        bx = t - by * (by + 1) / 2;           // bx <= by
    } else {
        bx = blockIdx.x; by = blockIdx.y;
    }
    int grow0 = row0 + by * 256;   // A rows (global)
    int gcol0 = bx * 256;          // B rows = C cols (global)
    int crow0 = grow0 - row0;      // C-buffer row base (panel-local in fallback)
    bool dgblk = (grow0 == gcol0); // the only block containing diag elements
    f32x4 acc[8][4] = {};

    int lr = lane >> 3;   // row within 8-row group
    int lc = lane & 7;    // LDS chunk slot this lane fills
    for (int kc = 0; kc < 8; ++kc) {
        #pragma unroll
        for (int tt = 0; tt < 4; ++tt) {
            int rb  = wv * 32 + tt * 8;    // wave-uniform row base
            int r   = rb + lr;
            int fch = lc ^ (r & 7);        // XOR chunk swizzle (conflict-free)
            async_ld16(xn + (size_t)(grow0 + r) * DIM + kc * 64 + fch * 8, &lA[rb * 64]);
            async_ld16(xn + (size_t)(gcol0 + r) * DIM + kc * 64 + fch * 8, &lB[rb * 64]);
        }
        __syncthreads();
        #pragma unroll
        for (int s = 0; s < 2; ++s) {
            bf16x8 af[8], bfr[4];
            #pragma unroll
            for (int i = 0; i < 8; ++i) {
                int ra = wr * 128 + i * 16 + m;
                af[i]  = *(const bf16x8*)&lA[ra * 64 + (((s * 4 + q) ^ (ra & 7)) * 8)];
            }
            #pragma unroll
            for (int j = 0; j < 4; ++j) {
                int rb2 = wc * 64 + j * 16 + m;
                bfr[j] = *(const bf16x8*)&lB[rb2 * 64 + (((s * 4 + q) ^ (rb2 & 7)) * 8)];
            }
            #pragma unroll
            for (int i = 0; i < 8; ++i)
                #pragma unroll
                for (int j = 0; j < 4; ++j)
                    acc[i][j] = __builtin_amdgcn_mfma_f32_16x16x32_bf16(af[i], bfr[j], acc[i][j], 0, 0, 0);
        }
        __syncthreads();
    }

    // ---- epilogue pass 1: M digest + mirror direct stores ----
    // C/D layout: col=lane&15 (m), row=q*4+reg (m89/m91-verified)
    u32* Cw = (u32*)C;
    const int NWd = NROWS / 2;                        // C row stride in dwords
    float cmf[2][4] = {{-3.0f,-3.0f,-3.0f,-3.0f},{-3.0f,-3.0f,-3.0f,-3.0f}};
    #pragma unroll
    for (int i = 0; i < 8; ++i) {
        float rmf[4] = {-3.0f, -3.0f, -3.0f, -3.0f};  // per-reg row maxima
        int rloc = wr * 128 + i * 16 + q * 4;         // local row (0..255)
        #pragma unroll
        for (int j = 0; j < 4; ++j) {
            int cl = wc * 64 + j * 16 + m;            // local col (0..255)
            int c  = gcol0 + cl;                      // global col
            ushort h[4];
            #pragma unroll
            for (int reg = 0; reg < 4; ++reg) {
                float a  = acc[i][j][reg];
                ushort hb = f2bf(a);
                float mv = a;
                if (dgblk && (grow0 + rloc + reg) == c) { hb = (ushort)0xC040; mv = -3.0f; }
                h[reg]   = hb;
                rmf[reg] = fmaxf(rmf[reg], mv);
                cmf[i >> 2][j] = fmaxf(cmf[i >> 2][j], mv);
            }
            if (TRI && !dgblk) {
                // mirror: C^T row = orig col; cols rloc..rloc+3 contiguous (8B)
                u32 p01 = (u32)h[0] | ((u32)h[1] << 16);
                u32 p23 = (u32)h[2] | ((u32)h[3] << 16);
                u64 pk  = (u64)p01 | ((u64)p23 << 32);
                *(u64*)(Cw + (size_t)(gcol0 + cl) * NWd + (u32)((grow0 + rloc) >> 1)) = pk;
            }
        }
        // row maxima: packed 2-rows/u32, reduce over the 16 m-lanes of each quad
        u32 kp01 = mkey(rmf[0]) | (mkey(rmf[1]) << 16);
        u32 kp23 = mkey(rmf[2]) | (mkey(rmf[3]) << 16);
        #pragma unroll
        for (int off = 1; off <= 8; off <<= 1) {
            kp01 = pkmax(kp01, (u32)__shfl_xor((int)kp01, off));
            kp23 = pkmax(kp23, (u32)__shfl_xor((int)kp23, off));
        }
        if (m == 0) {
            size_t mb = (size_t)(grow0 + rloc) * 128 + bx * 4 + wc;
            M[mb]       = (ushort)(kp01 & 0xFFFFu);
            M[mb + 128] = (ushort)(kp01 >> 16);
            M[mb + 256] = (ushort)(kp23 & 0xFFFFu);
            M[mb + 384] = (ushort)(kp23 >> 16);
        }
    }
    if (TRI && !dgblk) {
        // col maxima (mirror rows): wave covers 2 segments (i<4 / i>=4)
        #pragma unroll
        for (int hf = 0; hf < 2; ++hf) {
            u32 q01 = mkey(cmf[hf][0]) | (mkey(cmf[hf][1]) << 16);
            u32 q23 = mkey(cmf[hf][2]) | (mkey(cmf[hf][3]) << 16);
            q01 = pkmax(q01, (u32)__shfl_xor((int)q01, 16));
            q01 = pkmax(q01, (u32)__shfl_xor((int)q01, 32));
            q23 = pkmax(q23, (u32)__shfl_xor((int)q23, 16));
            q23 = pkmax(q23, (u32)__shfl_xor((int)q23, 32));
            if (q == 0) {
                int gc = gcol0 + wc * 64 + m;
                int sg = by * 4 + wr * 2 + hf;
                M[(size_t)(gc +  0) * 128 + sg] = (ushort)(q01 & 0xFFFFu);
                M[(size_t)(gc + 16) * 128 + sg] = (ushort)(q01 >> 16);
                M[(size_t)(gc + 32) * 128 + sg] = (ushort)(q23 & 0xFFFFu);
                M[(size_t)(gc + 48) * 128 + sg] = (ushort)(q23 >> 16);
            }
        }
    }

    // ---- epilogue pass 2: row tile via LDS, two 64KB halves ----
    // dword-XOR swizzle D = r*128 + (cd ^ (qr<<3)), qr=(r>>2)&3: scalar writes
    // conflict-free (bits 3-4 from j^qr, bits 0-2 from m>>1), b128 readback
    // stays 16B-aligned and rows contiguous.
    u32* sh32 = (u32*)sh;
    int tr = tid >> 5, tc = tid & 31;
    #pragma unroll
    for (int hf = 0; hf < 2; ++hf) {
        __syncthreads();
        if (wr == hf) {
            #pragma unroll
            for (int i = 0; i < 8; ++i) {
                int rl0 = i * 16 + q * 4;            // row within half (0..127)
                #pragma unroll
                for (int j = 0; j < 4; ++j) {
                    int cl = wc * 64 + j * 16 + m;
                    #pragma unroll
                    for (int reg = 0; reg < 4; ++reg) {
                        int r = rl0 + reg;
                        float a = acc[i][j][reg];
                        ushort hb = f2bf(a);
                        if (dgblk && (hf * 128 + r) == cl) hb = (ushort)0xC040;
                        int qr = (r >> 2) & 3;
                        int D  = r * 128 + ((cl >> 1) ^ (qr << 3));
                        sh[D * 2 + (cl & 1)] = hb;
                    }
                }
            }
        }
        __syncthreads();
        #pragma unroll
        for (int p = 0; p < 8; ++p) {
            int r  = p * 16 + tr;
            int qr = (r >> 2) & 3;
            uint4 v = *(const uint4*)&sh32[r * 128 + ((tc * 4) ^ (qr << 3))];
            *(uint4*)&C[(size_t)(crow0 + hf * 128 + r) * NROWS + gcol0 + tc * 8] = v;
        }
    }
}

// ---------------- select: ballot-bsearch top-20 + BCE ------------------------
__global__ __launch_bounds__(256) void k_select(const ushort* __restrict__ C,
                                                const ushort* __restrict__ M,
                                                const int* __restrict__ labels,
                                                int row0,
                                                float* __restrict__ partials) {
    __shared__ u32 s_surv[4][NSURV];
    __shared__ u32 s_seg[4][128];
    __shared__ u32 s_cnt[4];
    __shared__ u32 s_scnt[4];
    int lane = threadIdx.x & 63;
    int wv   = threadIdx.x >> 6;
    int prow = blockIdx.x * 4 + wv;
    int grow = row0 + prow;
    const ushort* rowC = C + (size_t)prow * NROWS;

    if (lane == 0) { s_cnt[wv] = 0; s_scnt[wv] = 0; }
    __syncthreads();

    // segment maxima (mono keys): lane holds segs 2*lane, 2*lane+1
    u32 pm  = *(const u32*)&M[(size_t)grow * 128 + 2 * lane];
    u32 klo = pm & 0xFFFFu, khi = pm >> 16;

    // T = largest 16-bit value with count(seg_max >= T) >= KSEL
    u32 T = 0;
    #pragma unroll
    for (int b = 15; b >= 0; --b) {
        u32 cand = T | (1u << b);
        int c = __popcll(__ballot(klo >= cand)) + __popcll(__ballot(khi >= cand));
        if (c >= KSEL) T = cand;
    }

    // survivor-segment id list in LDS
    if (klo >= T) { u32 p = atomicAdd(&s_scnt[wv], 1u); s_seg[wv][p] = 2u * lane; }
    if (khi >= T) { u32 p = atomicAdd(&s_scnt[wv], 1u); s_seg[wv][p] = 2u * lane + 1u; }
    u32 nseg = s_scnt[wv];
    int grp = lane >> 3, sub = lane & 7;   // 8 lanes per segment

    // fast path: up to 32 segments as 4 independent uint4 loads
    int  sid[4];
    uint4 vv[4];
    #pragma unroll
    for (int t = 0; t < 4; ++t) {
        u32 ix = (u32)(t * 8 + grp);
        sid[t] = (ix < nseg) ? (int)s_seg[wv][ix] : -1;
    }
    #pragma unroll
    for (int t = 0; t < 4; ++t) {
        if (sid[t] >= 0) vv[t] = *(const uint4*)(rowC + sid[t] * 64 + sub * 8);
    }
    #pragma unroll
    for (int t = 0; t < 4; ++t) {
        if (sid[t] < 0) continue;
        u32 wds[4] = { vv[t].x, vv[t].y, vv[t].z, vv[t].w };
        u32 cbase = (u32)(sid[t] * 64 + sub * 8);
        #pragma unroll
        for (int h = 0; h < 4; ++h) {
            u32 w  = wds[h];
            u32 kA = mono16(w & 0xFFFFu);
            u32 kB = mono16(w >> 16);
            if (kA >= T) { u32 p = atomicAdd(&s_cnt[wv], 1u); if (p < NSURV) s_surv[wv][p] = (kA << 16) | (cbase + 2u * h); }
            if (kB >= T) { u32 p = atomicAdd(&s_cnt[wv], 1u); if (p < NSURV) s_surv[wv][p] = (kB << 16) | (cbase + 2u * h + 1u); }
        }
    }
    // rare tail: nseg > 32
    for (u32 base = 32; base < nseg; base += 8) {
        u32 ix = base + (u32)grp;
        if (ix >= nseg) continue;
        int s = (int)s_seg[wv][ix];
        uint4 v = *(const uint4*)(rowC + s * 64 + sub * 8);
        u32 wds[4] = { v.x, v.y, v.z, v.w };
        u32 cbase = (u32)(s * 64 + sub * 8);
        #pragma unroll
        for (int h = 0; h < 4; ++h) {
            u32 w  = wds[h];
            u32 kA = mono16(w & 0xFFFFu);
            u32 kB = mono16(w >> 16);
            if (kA >= T) { u32 p = atomicAdd(&s_cnt[wv], 1u); if (p < NSURV) s_surv[wv][p] = (kA << 16) | (cbase + 2u * h); }
            if (kB >= T) { u32 p = atomicAdd(&s_cnt[wv], 1u); if (p < NSURV) s_surv[wv][p] = (kB << 16) | (cbase + 2u * h + 1u); }
        }
    }

    u32 cnt = min(s_cnt[wv], (u32)NSURV);     // same-wave LDS: ordered
    int mylab = labels[grow];
    float loss = 0.0f;

    if (cnt <= 64u) {
        // fast path: one survivor per lane; bsearch = 16 ballots
        u32 gg  = ((u32)lane < cnt) ? s_surv[wv][lane] : 0u;
        u32 key = gg >> 16;
        u32 V = 0;
        #pragma unroll
        for (int b = 15; b >= 0; --b) {
            u32 cand = V | (1u << b);
            if (__popcll(__ballot(key >= cand)) >= KSEL) V = cand;
        }
        int cgt  = __popcll(__ballot(key > V));
        int ceq  = __popcll(__ballot(gg != 0 && key == V));
        int need = KSEL - cgt;
        bool incl;
        if (ceq == need) {
            incl = (gg != 0) && (key >= V);
        } else {
            // more ties than slots: take `need` largest cols among ties
            u32 col = gg & 0xFFFFu;
            bool tie = (gg != 0) && (key == V);
            u32 Cv = 0;
            #pragma unroll
            for (int b = 15; b >= 0; --b) {
                u32 cand2 = Cv | (1u << b);
                if (__popcll(__ballot(tie && col >= cand2)) >= need) Cv = cand2;
            }
            incl = (key > V) || (tie && col >= Cv);   // cols unique -> exact
        }
        if (incl) {
            u32 col = gg & 0xFFFFu;
            u32 raw = (key & 0x8000u) ? (key ^ 0x8000u) : (key ^ 0xFFFFu);
            float v = __uint_as_float(raw << 16);
            float p = (v + 1.0f) * 0.5f;
            bool tm = (labels[col] == mylab);
            loss -= tm ? fmaxf(logf(p), -100.0f) : fmaxf(log1pf(-p), -100.0f);
        }
    } else {
        // fallback (rare): 8 survivors per lane
        u32 g[8];
        #pragma unroll
        for (int j = 0; j < 8; ++j) {
            u32 idx = (u32)lane + (u32)j * 64u;
            g[j] = (idx < cnt) ? s_surv[wv][idx] : 0u;
        }
        u32 V = 0;
        #pragma unroll
        for (int b = 15; b >= 0; --b) {
            u32 cand = V | (1u << b);
            int c = 0;
            #pragma unroll
            for (int j = 0; j < 8; ++j)
                c += __popcll(__ballot((g[j] >> 16) >= cand));
            if (c >= KSEL) V = cand;
        }
        int cgt = 0, ceq = 0;
        #pragma unroll
        for (int j = 0; j < 8; ++j) {
            cgt += __popcll(__ballot(g[j] != 0 && (g[j] >> 16) > V));
            ceq += __popcll(__ballot(g[j] != 0 && (g[j] >> 16) == V));
        }
        int need = KSEL - cgt;
        bool all_ties = (ceq == need);
        #pragma unroll
        for (int j = 0; j < 8; ++j) {
            u32 key = g[j] >> 16, col = g[j] & 0xFFFFu;
            if (g[j] != 0 && (key > V || (all_ties && key == V))) {
                u32 raw = (key & 0x8000u) ? (key ^ 0x8000u) : (key ^ 0xFFFFu);
                float v = __uint_as_float(raw << 16);
                float p = (v + 1.0f) * 0.5f;
                bool tm = (labels[col] == mylab);
                loss -= tm ? fmaxf(logf(p), -100.0f) : fmaxf(log1pf(-p), -100.0f);
            }
        }
        if (!all_ties) {
            for (int r = 0; r < need; ++r) {
                u32 best = 0;
                #pragma unroll
                for (int j = 0; j < 8; ++j) {
                    u32 c2 = (g[j] != 0 && (g[j] >> 16) == V) ? ((g[j] & 0xFFFFu) + 1u) : 0u;
                    best = max(best, c2);
                }
                #pragma unroll
                for (int off = 32; off; off >>= 1) best = max(best, (u32)__shfl_xor((int)best, off));
                #pragma unroll
                for (int j = 0; j < 8; ++j) {
                    if (g[j] != 0 && (g[j] >> 16) == V && ((g[j] & 0xFFFFu) + 1u) == best) {
                        u32 col = g[j] & 0xFFFFu;
                        u32 raw = (V & 0x8000u) ? (V ^ 0x8000u) : (V ^ 0xFFFFu);
                        float v = __uint_as_float(raw << 16);
                        float p = (v + 1.0f) * 0.5f;
                        bool tm = (labels[col] == mylab);
                        loss -= tm ? fmaxf(logf(p), -100.0f) : fmaxf(log1pf(-p), -100.0f);
                        g[j] = 0;
                    }
                }
            }
        }
    }

    #pragma unroll
    for (int off = 32; off; off >>= 1) loss += __shfl_xor(loss, off);
    if (lane == 0) partials[grow] = loss;
}

__global__ __launch_bounds__(256) void k_final(const float* __restrict__ partials,
                                               float* __restrict__ out) {
    __shared__ float s[4];
    int tid = threadIdx.x, lane = tid & 63, wvi = tid >> 6;
    const float4* p4 = (const float4*)partials;
    float sum = 0.0f;
    #pragma unroll
    for (int i = 0; i < 8; ++i) {
        float4 v = p4[tid + i * 256];
        sum += v.x + v.y + v.z + v.w;
    }
    #pragma unroll
    for (int off = 32; off; off >>= 1) sum += __shfl_xor(sum, off);
    if (lane == 0) s[wvi] = sum;
    __syncthreads();
    if (tid == 0) out[0] = (s[0] + s[1] + s[2] + s[3]) * (1.0f / (float)(NROWS * KSEL));
}

extern "C" void kernel_launch(void* const* d_in, const int* in_sizes, int n_in,
                              void* d_out, int out_size, void* d_ws, size_t ws_size,
                              hipStream_t stream) {
    const float* batch  = (const float*)d_in[0];
    const int*   labels = (const int*)d_in[1];

    ushort* xn = (ushort*)d_ws;
    ushort* C  = xn + (size_t)NROWS * DIM;
    // M (2 MB) and partials (32 KB) live in the batch input buffer (16 MB):
    // batch is fully consumed by k_norm before k_gemm/k_select write them.
    ushort* M        = (ushort*)d_in[0];
    float*  partials = (float*)((char*)d_in[0] + (4u << 20));

    size_t need_full = (size_t)NROWS * DIM * 2 + (size_t)NROWS * NROWS * 2;

    k_norm<<<NROWS / 4, 256, 0, stream>>>(batch, xn);

    if (ws_size >= need_full) {
        // full symmetric path: 528 lower-triangle 256^2 blocks, one select pass
        k_gemm<true><<<dim3(32 * 33 / 2), 512, 0, stream>>>(xn, C, M, 0);
        k_select<<<NROWS / 4, 256, 0, stream>>>(C, M, labels, 0, partials);
    } else {
        // fallback: panel path (24 MB of ws)
        for (int p = 0; p < NROWS / PANEL; ++p) {
            k_gemm<false><<<dim3(32, PANEL / 256), 512, 0, stream>>>(xn, C, M, p * PANEL);
            k_select<<<PANEL / 4, 256, 0, stream>>>(C, M, labels, p * PANEL, partials);
        }
    }
    k_final<<<1, 256, 0, stream>>>(partials, (float*)d_out);
}

// Round 3
// 189.634 us; speedup vs baseline: 1.2282x; 1.0860x over previous
//
#include <hip/hip_runtime.h>
#include <hip/hip_bf16.h>

#define NROWS 8192
#define DIM   512
#define KSEL  20
#define PANEL 1024
#define NSURV 512

typedef unsigned int u32;
typedef unsigned long long u64;
typedef short bf16x8 __attribute__((ext_vector_type(8)));
typedef float f32x4 __attribute__((ext_vector_type(4)));
typedef ushort u16x2 __attribute__((ext_vector_type(2)));

typedef const void __attribute__((address_space(1))) as1_void;
typedef void __attribute__((address_space(3))) as3_void;

__device__ __forceinline__ void async_ld16(const ushort* g, ushort* l) {
    __builtin_amdgcn_global_load_lds((as1_void*)g, (as3_void*)l, 16, 0, 0);
}

// round-to-nearest-even f32 -> bf16 bits
__device__ __forceinline__ ushort f2bf(float f) {
    u32 u = __float_as_uint(f);
    return (ushort)((u + 0x7FFFu + ((u >> 16) & 1u)) >> 16);
}

// monotone map for one u16 bf16 pattern: integer compare == float compare
__device__ __forceinline__ u32 mono16(u32 r) {
    return r ^ (0x8000u | ((r >> 15) * 0x7FFFu));
}

__device__ __forceinline__ u32 mkey(float f) { return mono16((u32)f2bf(f)); }

// packed u16x2 max
__device__ __forceinline__ u32 pkmax(u32 a, u32 b) {
    union { u32 u; u16x2 v; } x, y; x.u = a; y.u = b;
    x.v = __builtin_elementwise_max(x.v, y.v);
    return x.u;
}

// ---------------- normalize: fp32 rows -> unit-norm bf16 rows ----------------
__global__ __launch_bounds__(256) void k_norm(const float* __restrict__ x,
                                              ushort* __restrict__ xn) {
    int lane = threadIdx.x & 63;
    int wv   = threadIdx.x >> 6;
    int row  = blockIdx.x * 4 + wv;
    const float4* xr = (const float4*)(x + (size_t)row * DIM);
    float4 a = xr[2 * lane];
    float4 b = xr[2 * lane + 1];
    float ss = a.x*a.x + a.y*a.y + a.z*a.z + a.w*a.w
             + b.x*b.x + b.y*b.y + b.z*b.z + b.w*b.w;
    #pragma unroll
    for (int off = 32; off; off >>= 1) ss += __shfl_xor(ss, off);
    float sc = 1.0f / fmaxf(sqrtf(ss), 1e-12f);
    float v[8] = {a.x*sc, a.y*sc, a.z*sc, a.w*sc, b.x*sc, b.y*sc, b.z*sc, b.w*sc};
    union { ushort u[8]; uint4 q; } o;
    #pragma unroll
    for (int i = 0; i < 8; ++i) o.u[i] = f2bf(v[i]);
    *(uint4*)(xn + (size_t)row * DIM + lane * 8) = o.q;
}

// ---------------- GEMM: C = Xn * Xn^T (bf16 out), diag = -3.0 ----------------
// 256x256 tile, 512 threads = 8 waves (2 wave-rows x 4 wave-cols), each wave a
// 128x64 output (8x4 subtiles of 16x16x32 bf16 MFMA).
// Epilogue: BOTH tiles staged through LDS so every HBM store is a full-line
// coalesced b128 (r0=149MB vs r1/r2 scattered=215MB write evidence):
//   row tile: two 64KB halves, scalar-swizzled stage (0 conflicts, r2-proven).
//   mirror:   two 64KB transposed halves, packed row-pair u64 stage at
//             XOR-swizzled dword cols (^ (r&7)<<2 keeps 16B readback chunks;
//             worst-case 4-way conflict ~1.58x, trivial vs scattered stores).
template<bool TRI>
__global__ __launch_bounds__(512, 2) void k_gemm(const ushort* __restrict__ xn,
                                                 ushort* __restrict__ C,
                                                 ushort* __restrict__ M,
                                                 int row0) {
    __shared__ ushort sh[2 * 256 * 64];      // 64 KB: K-loop A|B; epi: half-tile
    ushort* lA = sh;
    ushort* lB = sh + 256 * 64;
    int tid  = threadIdx.x;
    int lane = tid & 63, wv = tid >> 6;       // wv 0..7
    int wr = wv >> 2, wc = wv & 3;            // 2 x 4 wave grid
    int q = lane >> 4, m = lane & 15;
    int bx, by;
    if (TRI) {
        int t = (int)blockIdx.x;
        t = (t & 7) * 66 + (t >> 3);          // XCD swizzle: 528 = 8*66 (bijective)
        by = (int)((sqrtf(8.0f * (float)t + 1.0f) - 1.0f) * 0.5f);
        while ((by + 1) * (by + 2) / 2 <= t) ++by;
        while (by * (by + 1) / 2 > t) --by;
        bx = t - by * (by + 1) / 2;           // bx <= by
    } else {
        bx = blockIdx.x; by = blockIdx.y;
    }
    int grow0 = row0 + by * 256;   // A rows (global)
    int gcol0 = bx * 256;          // B rows = C cols (global)
    int crow0 = grow0 - row0;      // C-buffer row base (panel-local in fallback)
    bool dgblk = (grow0 == gcol0); // the only block containing diag elements
    f32x4 acc[8][4] = {};

    int lr = lane >> 3;   // row within 8-row group
    int lc = lane & 7;    // LDS chunk slot this lane fills
    for (int kc = 0; kc < 8; ++kc) {
        #pragma unroll
        for (int tt = 0; tt < 4; ++tt) {
            int rb  = wv * 32 + tt * 8;    // wave-uniform row base
            int r   = rb + lr;
            int fch = lc ^ (r & 7);        // XOR chunk swizzle (conflict-free)
            async_ld16(xn + (size_t)(grow0 + r) * DIM + kc * 64 + fch * 8, &lA[rb * 64]);
            async_ld16(xn + (size_t)(gcol0 + r) * DIM + kc * 64 + fch * 8, &lB[rb * 64]);
        }
        __syncthreads();
        #pragma unroll
        for (int s = 0; s < 2; ++s) {
            bf16x8 af[8], bfr[4];
            #pragma unroll
            for (int i = 0; i < 8; ++i) {
                int ra = wr * 128 + i * 16 + m;
                af[i]  = *(const bf16x8*)&lA[ra * 64 + (((s * 4 + q) ^ (ra & 7)) * 8)];
            }
            #pragma unroll
            for (int j = 0; j < 4; ++j) {
                int rb2 = wc * 64 + j * 16 + m;
                bfr[j] = *(const bf16x8*)&lB[rb2 * 64 + (((s * 4 + q) ^ (rb2 & 7)) * 8)];
            }
            #pragma unroll
            for (int i = 0; i < 8; ++i)
                #pragma unroll
                for (int j = 0; j < 4; ++j)
                    acc[i][j] = __builtin_amdgcn_mfma_f32_16x16x32_bf16(af[i], bfr[j], acc[i][j], 0, 0, 0);
        }
        __syncthreads();
    }

    // ---- epilogue pass 1: register-only maxima digest + M stores ----
    // C/D layout: col=lane&15 (m), row=q*4+reg (m89/m91-verified)
    float cmf[2][4] = {{-3.0f,-3.0f,-3.0f,-3.0f},{-3.0f,-3.0f,-3.0f,-3.0f}};
    #pragma unroll
    for (int i = 0; i < 8; ++i) {
        float rmf[4] = {-3.0f, -3.0f, -3.0f, -3.0f};  // per-reg row maxima
        int rloc = wr * 128 + i * 16 + q * 4;         // local row (0..255)
        #pragma unroll
        for (int j = 0; j < 4; ++j) {
            int cl = wc * 64 + j * 16 + m;            // local col (0..255)
            int c  = gcol0 + cl;                      // global col
            #pragma unroll
            for (int reg = 0; reg < 4; ++reg) {
                float a  = acc[i][j][reg];
                float mv = (dgblk && (grow0 + rloc + reg) == c) ? -3.0f : a;
                rmf[reg] = fmaxf(rmf[reg], mv);
                cmf[i >> 2][j] = fmaxf(cmf[i >> 2][j], mv);
            }
        }
        // row maxima: packed 2-rows/u32, reduce over the 16 m-lanes of each quad
        u32 kp01 = mkey(rmf[0]) | (mkey(rmf[1]) << 16);
        u32 kp23 = mkey(rmf[2]) | (mkey(rmf[3]) << 16);
        #pragma unroll
        for (int off = 1; off <= 8; off <<= 1) {
            kp01 = pkmax(kp01, (u32)__shfl_xor((int)kp01, off));
            kp23 = pkmax(kp23, (u32)__shfl_xor((int)kp23, off));
        }
        if (m == 0) {
            size_t mb = (size_t)(grow0 + rloc) * 128 + bx * 4 + wc;
            M[mb]       = (ushort)(kp01 & 0xFFFFu);
            M[mb + 128] = (ushort)(kp01 >> 16);
            M[mb + 256] = (ushort)(kp23 & 0xFFFFu);
            M[mb + 384] = (ushort)(kp23 >> 16);
        }
    }
    if (TRI && !dgblk) {
        // col maxima (mirror rows): wave covers 2 segments (i<4 / i>=4)
        #pragma unroll
        for (int hf = 0; hf < 2; ++hf) {
            u32 q01 = mkey(cmf[hf][0]) | (mkey(cmf[hf][1]) << 16);
            u32 q23 = mkey(cmf[hf][2]) | (mkey(cmf[hf][3]) << 16);
            q01 = pkmax(q01, (u32)__shfl_xor((int)q01, 16));
            q01 = pkmax(q01, (u32)__shfl_xor((int)q01, 32));
            q23 = pkmax(q23, (u32)__shfl_xor((int)q23, 16));
            q23 = pkmax(q23, (u32)__shfl_xor((int)q23, 32));
            if (q == 0) {
                int gc = gcol0 + wc * 64 + m;
                int sg = by * 4 + wr * 2 + hf;
                M[(size_t)(gc +  0) * 128 + sg] = (ushort)(q01 & 0xFFFFu);
                M[(size_t)(gc + 16) * 128 + sg] = (ushort)(q01 >> 16);
                M[(size_t)(gc + 32) * 128 + sg] = (ushort)(q23 & 0xFFFFu);
                M[(size_t)(gc + 48) * 128 + sg] = (ushort)(q23 >> 16);
            }
        }
    }

    // ---- epilogue pass 2: row tile via LDS, two 64KB halves (r2-proven) ----
    // dword-XOR swizzle D = r*128 + (cd ^ (qr<<3)), qr=(r>>2)&3: scalar writes
    // conflict-free, b128 readback 16B-aligned + rows contiguous.
    u32* sh32 = (u32*)sh;
    int tr = tid >> 5, tc = tid & 31;
    #pragma unroll
    for (int hf = 0; hf < 2; ++hf) {
        __syncthreads();
        if (wr == hf) {
            #pragma unroll
            for (int i = 0; i < 8; ++i) {
                int rl0 = i * 16 + q * 4;            // row within half (0..127)
                #pragma unroll
                for (int j = 0; j < 4; ++j) {
                    int cl = wc * 64 + j * 16 + m;
                    #pragma unroll
                    for (int reg = 0; reg < 4; ++reg) {
                        int r = rl0 + reg;
                        float a = acc[i][j][reg];
                        ushort hb = f2bf(a);
                        if (dgblk && (hf * 128 + r) == cl) hb = (ushort)0xC040;
                        int qr = (r >> 2) & 3;
                        int D  = r * 128 + ((cl >> 1) ^ (qr << 3));
                        sh[D * 2 + (cl & 1)] = hb;
                    }
                }
            }
        }
        __syncthreads();
        #pragma unroll
        for (int p = 0; p < 8; ++p) {
            int r  = p * 16 + tr;
            int qr = (r >> 2) & 3;
            uint4 v = *(const uint4*)&sh32[r * 128 + ((tc * 4) ^ (qr << 3))];
            *(uint4*)&C[(size_t)(crow0 + hf * 128 + r) * NROWS + gcol0 + tc * 8] = v;
        }
    }

    // ---- epilogue pass 3: mirror (C^T) via LDS, two transposed halves ----
    // Stage: waves with wc>>1==hf hold cols of this half. Per (i,j): packed
    // row-pair u64 at C^T row rT = (wc&1)*64+j*16+m, dword col c0 = wr*64+i*8
    // +q*2, swizzled c0 ^ ((rT&7)<<2) (multiple of 4 dwords -> b128 readback
    // chunks preserved). Readback+store: identical coalesced shape to pass 2.
    if (TRI && !dgblk) {
        #pragma unroll
        for (int hf = 0; hf < 2; ++hf) {
            __syncthreads();
            if ((wc >> 1) == hf) {
                int rT = (wc & 1) * 64 + m;          // C^T row within half, +j*16
                #pragma unroll
                for (int i = 0; i < 8; ++i) {
                    int c0 = wr * 64 + i * 8 + q * 2; // dword col (rows rloc..+3)
                    #pragma unroll
                    for (int j = 0; j < 4; ++j) {
                        int r2 = rT + j * 16;
                        u32 p01 = (u32)f2bf(acc[i][j][0]) | ((u32)f2bf(acc[i][j][1]) << 16);
                        u32 p23 = (u32)f2bf(acc[i][j][2]) | ((u32)f2bf(acc[i][j][3]) << 16);
                        u64 pk  = (u64)p01 | ((u64)p23 << 32);
                        *(u64*)&sh32[r2 * 128 + (c0 ^ ((r2 & 7) << 2))] = pk;
                    }
                }
            }
            __syncthreads();
            #pragma unroll
            for (int p = 0; p < 8; ++p) {
                int r2 = p * 16 + tr;
                uint4 v = *(const uint4*)&sh32[r2 * 128 + ((tc * 4) ^ ((r2 & 7) << 2))];
                *(uint4*)&C[(size_t)(gcol0 + hf * 128 + r2) * NROWS + grow0 + tc * 8] = v;
            }
        }
    }
}

// ---------------- select: ballot-bsearch top-20 + BCE ------------------------
__global__ __launch_bounds__(256) void k_select(const ushort* __restrict__ C,
                                                const ushort* __restrict__ M,
                                                const int* __restrict__ labels,
                                                int row0,
                                                float* __restrict__ partials) {
    __shared__ u32 s_surv[4][NSURV];
    __shared__ u32 s_seg[4][128];
    __shared__ u32 s_cnt[4];
    __shared__ u32 s_scnt[4];
    int lane = threadIdx.x & 63;
    int wv   = threadIdx.x >> 6;
    int prow = blockIdx.x * 4 + wv;
    int grow = row0 + prow;
    const ushort* rowC = C + (size_t)prow * NROWS;

    if (lane == 0) { s_cnt[wv] = 0; s_scnt[wv] = 0; }
    __syncthreads();

    // segment maxima (mono keys): lane holds segs 2*lane, 2*lane+1
    u32 pm  = *(const u32*)&M[(size_t)grow * 128 + 2 * lane];
    u32 klo = pm & 0xFFFFu, khi = pm >> 16;

    // T = largest 16-bit value with count(seg_max >= T) >= KSEL
    u32 T = 0;
    #pragma unroll
    for (int b = 15; b >= 0; --b) {
        u32 cand = T | (1u << b);
        int c = __popcll(__ballot(klo >= cand)) + __popcll(__ballot(khi >= cand));
        if (c >= KSEL) T = cand;
    }

    // survivor-segment id list in LDS
    if (klo >= T) { u32 p = atomicAdd(&s_scnt[wv], 1u); s_seg[wv][p] = 2u * lane; }
    if (khi >= T) { u32 p = atomicAdd(&s_scnt[wv], 1u); s_seg[wv][p] = 2u * lane + 1u; }
    u32 nseg = s_scnt[wv];
    int grp = lane >> 3, sub = lane & 7;   // 8 lanes per segment

    // fast path: up to 32 segments as 4 independent uint4 loads
    int  sid[4];
    uint4 vv[4];
    #pragma unroll
    for (int t = 0; t < 4; ++t) {
        u32 ix = (u32)(t * 8 + grp);
        sid[t] = (ix < nseg) ? (int)s_seg[wv][ix] : -1;
    }
    #pragma unroll
    for (int t = 0; t < 4; ++t) {
        if (sid[t] >= 0) vv[t] = *(const uint4*)(rowC + sid[t] * 64 + sub * 8);
    }
    #pragma unroll
    for (int t = 0; t < 4; ++t) {
        if (sid[t] < 0) continue;
        u32 wds[4] = { vv[t].x, vv[t].y, vv[t].z, vv[t].w };
        u32 cbase = (u32)(sid[t] * 64 + sub * 8);
        #pragma unroll
        for (int h = 0; h < 4; ++h) {
            u32 w  = wds[h];
            u32 kA = mono16(w & 0xFFFFu);
            u32 kB = mono16(w >> 16);
            if (kA >= T) { u32 p = atomicAdd(&s_cnt[wv], 1u); if (p < NSURV) s_surv[wv][p] = (kA << 16) | (cbase + 2u * h); }
            if (kB >= T) { u32 p = atomicAdd(&s_cnt[wv], 1u); if (p < NSURV) s_surv[wv][p] = (kB << 16) | (cbase + 2u * h + 1u); }
        }
    }
    // rare tail: nseg > 32
    for (u32 base = 32; base < nseg; base += 8) {
        u32 ix = base + (u32)grp;
        if (ix >= nseg) continue;
        int s = (int)s_seg[wv][ix];
        uint4 v = *(const uint4*)(rowC + s * 64 + sub * 8);
        u32 wds[4] = { v.x, v.y, v.z, v.w };
        u32 cbase = (u32)(s * 64 + sub * 8);
        #pragma unroll
        for (int h = 0; h < 4; ++h) {
            u32 w  = wds[h];
            u32 kA = mono16(w & 0xFFFFu);
            u32 kB = mono16(w >> 16);
            if (kA >= T) { u32 p = atomicAdd(&s_cnt[wv], 1u); if (p < NSURV) s_surv[wv][p] = (kA << 16) | (cbase + 2u * h); }
            if (kB >= T) { u32 p = atomicAdd(&s_cnt[wv], 1u); if (p < NSURV) s_surv[wv][p] = (kB << 16) | (cbase + 2u * h + 1u); }
        }
    }

    u32 cnt = min(s_cnt[wv], (u32)NSURV);     // same-wave LDS: ordered
    int mylab = labels[grow];
    float loss = 0.0f;

    if (cnt <= 64u) {
        // fast path: one survivor per lane; bsearch = 16 ballots
        u32 gg  = ((u32)lane < cnt) ? s_surv[wv][lane] : 0u;
        u32 key = gg >> 16;
        u32 V = 0;
        #pragma unroll
        for (int b = 15; b >= 0; --b) {
            u32 cand = V | (1u << b);
            if (__popcll(__ballot(key >= cand)) >= KSEL) V = cand;
        }
        int cgt  = __popcll(__ballot(key > V));
        int ceq  = __popcll(__ballot(gg != 0 && key == V));
        int need = KSEL - cgt;
        bool incl;
        if (ceq == need) {
            incl = (gg != 0) && (key >= V);
        } else {
            // more ties than slots: take `need` largest cols among ties
            u32 col = gg & 0xFFFFu;
            bool tie = (gg != 0) && (key == V);
            u32 Cv = 0;
            #pragma unroll
            for (int b = 15; b >= 0; --b) {
                u32 cand2 = Cv | (1u << b);
                if (__popcll(__ballot(tie && col >= cand2)) >= need) Cv = cand2;
            }
            incl = (key > V) || (tie && col >= Cv);   // cols unique -> exact
        }
        if (incl) {
            u32 col = gg & 0xFFFFu;
            u32 raw = (key & 0x8000u) ? (key ^ 0x8000u) : (key ^ 0xFFFFu);
            float v = __uint_as_float(raw << 16);
            float p = (v + 1.0f) * 0.5f;
            bool tm = (labels[col] == mylab);
            loss -= tm ? fmaxf(logf(p), -100.0f) : fmaxf(log1pf(-p), -100.0f);
        }
    } else {
        // fallback (rare): 8 survivors per lane
        u32 g[8];
        #pragma unroll
        for (int j = 0; j < 8; ++j) {
            u32 idx = (u32)lane + (u32)j * 64u;
            g[j] = (idx < cnt) ? s_surv[wv][idx] : 0u;
        }
        u32 V = 0;
        #pragma unroll
        for (int b = 15; b >= 0; --b) {
            u32 cand = V | (1u << b);
            int c = 0;
            #pragma unroll
            for (int j = 0; j < 8; ++j)
                c += __popcll(__ballot((g[j] >> 16) >= cand));
            if (c >= KSEL) V = cand;
        }
        int cgt = 0, ceq = 0;
        #pragma unroll
        for (int j = 0; j < 8; ++j) {
            cgt += __popcll(__ballot(g[j] != 0 && (g[j] >> 16) > V));
            ceq += __popcll(__ballot(g[j] != 0 && (g[j] >> 16) == V));
        }
        int need = KSEL - cgt;
        bool all_ties = (ceq == need);
        #pragma unroll
        for (int j = 0; j < 8; ++j) {
            u32 key = g[j] >> 16, col = g[j] & 0xFFFFu;
            if (g[j] != 0 && (key > V || (all_ties && key == V))) {
                u32 raw = (key & 0x8000u) ? (key ^ 0x8000u) : (key ^ 0xFFFFu);
                float v = __uint_as_float(raw << 16);
                float p = (v + 1.0f) * 0.5f;
                bool tm = (labels[col] == mylab);
                loss -= tm ? fmaxf(logf(p), -100.0f) : fmaxf(log1pf(-p), -100.0f);
            }
        }
        if (!all_ties) {
            for (int r = 0; r < need; ++r) {
                u32 best = 0;
                #pragma unroll
                for (int j = 0; j < 8; ++j) {
                    u32 c2 = (g[j] != 0 && (g[j] >> 16) == V) ? ((g[j] & 0xFFFFu) + 1u) : 0u;
                    best = max(best, c2);
                }
                #pragma unroll
                for (int off = 32; off; off >>= 1) best = max(best, (u32)__shfl_xor((int)best, off));
                #pragma unroll
                for (int j = 0; j < 8; ++j) {
                    if (g[j] != 0 && (g[j] >> 16) == V && ((g[j] & 0xFFFFu) + 1u) == best) {
                        u32 col = g[j] & 0xFFFFu;
                        u32 raw = (V & 0x8000u) ? (V ^ 0x8000u) : (V ^ 0xFFFFu);
                        float v = __uint_as_float(raw << 16);
                        float p = (v + 1.0f) * 0.5f;
                        bool tm = (labels[col] == mylab);
                        loss -= tm ? fmaxf(logf(p), -100.0f) : fmaxf(log1pf(-p), -100.0f);
                        g[j] = 0;
                    }
                }
            }
        }
    }

    #pragma unroll
    for (int off = 32; off; off >>= 1) loss += __shfl_xor(loss, off);
    if (lane == 0) partials[grow] = loss;
}

__global__ __launch_bounds__(256) void k_final(const float* __restrict__ partials,
                                               float* __restrict__ out) {
    __shared__ float s[4];
    int tid = threadIdx.x, lane = tid & 63, wvi = tid >> 6;
    const float4* p4 = (const float4*)partials;
    float sum = 0.0f;
    #pragma unroll
    for (int i = 0; i < 8; ++i) {
        float4 v = p4[tid + i * 256];
        sum += v.x + v.y + v.z + v.w;
    }
    #pragma unroll
    for (int off = 32; off; off >>= 1) sum += __shfl_xor(sum, off);
    if (lane == 0) s[wvi] = sum;
    __syncthreads();
    if (tid == 0) out[0] = (s[0] + s[1] + s[2] + s[3]) * (1.0f / (float)(NROWS * KSEL));
}

extern "C" void kernel_launch(void* const* d_in, const int* in_sizes, int n_in,
                              void* d_out, int out_size, void* d_ws, size_t ws_size,
                              hipStream_t stream) {
    const float* batch  = (const float*)d_in[0];
    const int*   labels = (const int*)d_in[1];

    ushort* xn = (ushort*)d_ws;
    ushort* C  = xn + (size_t)NROWS * DIM;
    // M (2 MB) and partials (32 KB) live in the batch input buffer (16 MB):
    // batch is fully consumed by k_norm before k_gemm/k_select write them.
    ushort* M        = (ushort*)d_in[0];
    float*  partials = (float*)((char*)d_in[0] + (4u << 20));

    size_t need_full = (size_t)NROWS * DIM * 2 + (size_t)NROWS * NROWS * 2;

    k_norm<<<NROWS / 4, 256, 0, stream>>>(batch, xn);

    if (ws_size >= need_full) {
        // full symmetric path: 528 lower-triangle 256^2 blocks, one select pass
        k_gemm<true><<<dim3(32 * 33 / 2), 512, 0, stream>>>(xn, C, M, 0);
        k_select<<<NROWS / 4, 256, 0, stream>>>(C, M, labels, 0, partials);
    } else {
        // fallback: panel path (24 MB of ws)
        for (int p = 0; p < NROWS / PANEL; ++p) {
            k_gemm<false><<<dim3(32, PANEL / 256), 512, 0, stream>>>(xn, C, M, p * PANEL);
            k_select<<<PANEL / 4, 256, 0, stream>>>(C, M, labels, p * PANEL, partials);
        }
    }
    k_final<<<1, 256, 0, stream>>>(partials, (float*)d_out);
}

// Round 4
// 158.322 us; speedup vs baseline: 1.4711x; 1.1978x over previous
//
#include <hip/hip_runtime.h>
#include <hip/hip_bf16.h>

#define NROWS 8192
#define DIM   512
#define KSEL  20
#define PANEL 1024
#define NSURV 512

typedef unsigned int u32;
typedef unsigned long long u64;
typedef short bf16x8 __attribute__((ext_vector_type(8)));
typedef float f32x4 __attribute__((ext_vector_type(4)));
typedef ushort u16x2 __attribute__((ext_vector_type(2)));

typedef const void __attribute__((address_space(1))) as1_void;
typedef void __attribute__((address_space(3))) as3_void;

__device__ __forceinline__ void async_ld16(const ushort* g, ushort* l) {
    __builtin_amdgcn_global_load_lds((as1_void*)g, (as3_void*)l, 16, 0, 0);
}

// round-to-nearest-even f32 -> bf16 bits
__device__ __forceinline__ ushort f2bf(float f) {
    u32 u = __float_as_uint(f);
    return (ushort)((u + 0x7FFFu + ((u >> 16) & 1u)) >> 16);
}

// monotone map for one u16 bf16 pattern: integer compare == float compare
__device__ __forceinline__ u32 mono16(u32 r) {
    return r ^ (0x8000u | ((r >> 15) * 0x7FFFu));
}

__device__ __forceinline__ u32 mkey(float f) { return mono16((u32)f2bf(f)); }

// packed u16x2 max
__device__ __forceinline__ u32 pkmax(u32 a, u32 b) {
    union { u32 u; u16x2 v; } x, y; x.u = a; y.u = b;
    x.v = __builtin_elementwise_max(x.v, y.v);
    return x.u;
}

// ---------------- normalize: fp32 rows -> unit-norm bf16 rows ----------------
__global__ __launch_bounds__(256) void k_norm(const float* __restrict__ x,
                                              ushort* __restrict__ xn) {
    int lane = threadIdx.x & 63;
    int wv   = threadIdx.x >> 6;
    int row  = blockIdx.x * 4 + wv;
    const float4* xr = (const float4*)(x + (size_t)row * DIM);
    float4 a = xr[2 * lane];
    float4 b = xr[2 * lane + 1];
    float ss = a.x*a.x + a.y*a.y + a.z*a.z + a.w*a.w
             + b.x*b.x + b.y*b.y + b.z*b.z + b.w*b.w;
    #pragma unroll
    for (int off = 32; off; off >>= 1) ss += __shfl_xor(ss, off);
    float sc = 1.0f / fmaxf(sqrtf(ss), 1e-12f);
    float v[8] = {a.x*sc, a.y*sc, a.z*sc, a.w*sc, b.x*sc, b.y*sc, b.z*sc, b.w*sc};
    union { ushort u[8]; uint4 q; } o;
    #pragma unroll
    for (int i = 0; i < 8; ++i) o.u[i] = f2bf(v[i]);
    *(uint4*)(xn + (size_t)row * DIM + lane * 8) = o.q;
}

// ---------------- GEMM: C = Xn * Xn^T (bf16 out), diag = -3.0 ----------------
// 128x128 tile, 4 waves (2x2), each wave 4x4 subtiles of 16x16x32 bf16 MFMA.
// (r0 structure, proven 94.5us: 4 blocks/CU VGPR-limited, 2080 blocks of
// cross-block overlap hide the 2-barrier K-loop drains. 256^2 variants were
// SLOWER at lower traffic -> latency-bound, residency wins.)
// Round-4 deltas vs r0: XCD-bijective triangle swizzle (2080=8*260) and
// TRANSPOSED M digest M[seg*NROWS+row] (contiguous u64 per wave-quad, kills
// the ~15MB M write-amplification from 2B scatter into shared lines).
template<bool TRI>
__global__ __launch_bounds__(256) void k_gemm(const ushort* __restrict__ xn,
                                              ushort* __restrict__ C,
                                              ushort* __restrict__ M,
                                              int row0) {
    __shared__ ushort sh[128 * 128];         // K-loop: A|B staging; epi: tile
    ushort* lA = sh;
    ushort* lB = sh + 128 * 64;
    int tid  = threadIdx.x;
    int lane = tid & 63, wv = tid >> 6;
    int wr = wv >> 1, wc = wv & 1;
    int q = lane >> 4, m = lane & 15;
    int bx, by;
    if (TRI) {
        int t = (int)blockIdx.x;
        t = (t & 7) * 260 + (t >> 3);        // XCD swizzle: 2080 = 8*260 (bijective)
        by = (int)((sqrtf(8.0f * (float)t + 1.0f) - 1.0f) * 0.5f);
        while ((by + 1) * (by + 2) / 2 <= t) ++by;
        while (by * (by + 1) / 2 > t) --by;
        bx = t - by * (by + 1) / 2;          // bx <= by
    } else {
        bx = blockIdx.x; by = blockIdx.y;
    }
    int grow0 = row0 + by * 128;   // A rows (global)
    int gcol0 = bx * 128;          // B rows = C cols (global)
    f32x4 acc[4][4] = {};

    int lr = lane >> 3;   // row within 8-row group
    int lc = lane & 7;    // LDS chunk slot this lane fills
    for (int kc = 0; kc < 8; ++kc) {
        #pragma unroll
        for (int t = 0; t < 4; ++t) {
            int rb  = wv * 32 + t * 8;     // wave-uniform row base
            int r   = rb + lr;
            int fch = lc ^ (r & 7);        // XOR chunk swizzle (bank-conflict-free)
            async_ld16(xn + (size_t)(grow0 + r) * DIM + kc * 64 + fch * 8, &lA[rb * 64]);
            async_ld16(xn + (size_t)(gcol0 + r) * DIM + kc * 64 + fch * 8, &lB[rb * 64]);
        }
        __syncthreads();
        #pragma unroll
        for (int s = 0; s < 2; ++s) {
            bf16x8 af[4], bfr[4];
            #pragma unroll
            for (int i = 0; i < 4; ++i) {
                int ra = wr * 64 + i * 16 + m;
                af[i]  = *(const bf16x8*)&lA[ra * 64 + (((s * 4 + q) ^ (ra & 7)) * 8)];
                int rb2 = wc * 64 + i * 16 + m;
                bfr[i] = *(const bf16x8*)&lB[rb2 * 64 + (((s * 4 + q) ^ (rb2 & 7)) * 8)];
            }
            #pragma unroll
            for (int i = 0; i < 4; ++i)
                #pragma unroll
                for (int j = 0; j < 4; ++j)
                    acc[i][j] = __builtin_amdgcn_mfma_f32_16x16x32_bf16(af[i], bfr[j], acc[i][j], 0, 0, 0);
        }
        __syncthreads();
    }

    // ---- epilogue phase 1: stage row-tile in LDS + M digest ----
    // C/D layout: col=lane&15, row=quad*4+reg (m89/m91-verified)
    float cmf[4] = {-3.0f, -3.0f, -3.0f, -3.0f};     // per-j col maxima
    #pragma unroll
    for (int i = 0; i < 4; ++i) {
        float rmf[4] = {-3.0f, -3.0f, -3.0f, -3.0f}; // per-reg row maxima
        int rloc = wr * 64 + i * 16 + q * 4;         // local row base (0..127)
        #pragma unroll
        for (int j = 0; j < 4; ++j) {
            int cl = wc * 64 + j * 16 + m;           // local col
            int c  = gcol0 + cl;                     // global col
            #pragma unroll
            for (int reg = 0; reg < 4; ++reg) {
                int r    = rloc + reg;
                int grw  = row0 + by * 128 + r;
                float a  = acc[i][j][reg];
                bool dg  = (grw == c);
                float mv = dg ? -3.0f : a;
                rmf[reg] = fmaxf(rmf[reg], mv);
                cmf[j]   = fmaxf(cmf[j], mv);
                // dword-swizzled row-tile write (conflict-free; q=(r>>2)&3)
                int D = r * 64 + ((cl >> 1) ^ (q << 3));
                sh[D * 2 + (cl & 1)] = dg ? (ushort)0xC040 : f2bf(a);
            }
        }
        // row maxima: packed 2-rows/u32, reduce over 16 lanes (m) of each quad
        u32 p01 = mkey(rmf[0]) | (mkey(rmf[1]) << 16);
        u32 p23 = mkey(rmf[2]) | (mkey(rmf[3]) << 16);
        #pragma unroll
        for (int off = 1; off <= 8; off <<= 1) {
            p01 = pkmax(p01, (u32)__shfl_xor((int)p01, off));
            p23 = pkmax(p23, (u32)__shfl_xor((int)p23, off));
        }
        if (m == 0) {
            // transposed M: seg-major, rows rloc..rloc+3 contiguous -> one u64
            u64 pk = (u64)p01 | ((u64)p23 << 32);
            *(u64*)&M[(size_t)(bx * 2 + wc) * NROWS + (row0 + by * 128 + rloc)] = pk;
        }
    }
    if (TRI && bx != by) {
        // col maxima (mirror rows): packed 2-cols/u32, reduce over quads (q)
        u32 q01 = mkey(cmf[0]) | (mkey(cmf[1]) << 16);
        u32 q23 = mkey(cmf[2]) | (mkey(cmf[3]) << 16);
        q01 = pkmax(q01, (u32)__shfl_xor((int)q01, 16));
        q01 = pkmax(q01, (u32)__shfl_xor((int)q01, 32));
        q23 = pkmax(q23, (u32)__shfl_xor((int)q23, 16));
        q23 = pkmax(q23, (u32)__shfl_xor((int)q23, 32));
        if (q == 0) {
            // transposed M: 16 m-lanes write 16 contiguous ushorts per group
            int gc = gcol0 + wc * 64 + m;
            size_t sb = (size_t)(by * 2 + wr) * NROWS + gc;
            M[sb +  0] = (ushort)(q01 & 0xFFFFu);
            M[sb + 16] = (ushort)(q01 >> 16);
            M[sb + 32] = (ushort)(q23 & 0xFFFFu);
            M[sb + 48] = (ushort)(q23 >> 16);
        }
    }
    __syncthreads();

    // ---- epilogue phase 2a: coalesced row-major readback & store ----
    int tr = tid >> 4;       // 0..15
    int tc = tid & 15;       // 8-col chunk
    #pragma unroll
    for (int p = 0; p < 8; ++p) {
        int r  = p * 16 + tr;
        int qr = (r >> 2) & 3;
        uint4 v = *(const uint4*)&sh[(r * 64 + ((tc * 4) ^ (qr << 3))) * 2];
        *(uint4*)&C[(size_t)(by * 128 + r) * NROWS + gcol0 + tc * 8] = v;
    }

    if (TRI && bx != by) {
        // ---- phase 2b: re-stage transposed tile (packed row-pair b32) ----
        __syncthreads();
        u32* sh32 = (u32*)sh;
        #pragma unroll
        for (int i = 0; i < 4; ++i) {
            int cd0 = wr * 32 + i * 8 + q * 2;       // C^T dword col (rows rloc..+1)
            #pragma unroll
            for (int j = 0; j < 4; ++j) {
                int rT = wc * 64 + j * 16 + m;       // C^T row = orig col
                int gT = ((rT >> 2) & 3) << 3;
                u32 w0 = (u32)f2bf(acc[i][j][0]) | ((u32)f2bf(acc[i][j][1]) << 16);
                u32 w1 = (u32)f2bf(acc[i][j][2]) | ((u32)f2bf(acc[i][j][3]) << 16);
                sh32[rT * 64 + (cd0 ^ gT)]       = w0;
                sh32[rT * 64 + ((cd0 + 1) ^ gT)] = w1;
            }
        }
        __syncthreads();
        // ---- phase 2c: coalesced transposed readback & store ----
        #pragma unroll
        for (int p = 0; p < 8; ++p) {
            int ct = p * 16 + tr;                    // mirror global row gcol0+ct
            int gq = ((ct >> 2) & 3) << 3;
            uint4 v = *(const uint4*)&sh32[ct * 64 + ((tc * 4) ^ gq)];
            *(uint4*)&C[(size_t)(gcol0 + ct) * NROWS + by * 128 + tc * 8] = v;
        }
    }
}

// ---------------- select: ballot-bsearch top-20 + BCE ------------------------
__global__ __launch_bounds__(256) void k_select(const ushort* __restrict__ C,
                                                const ushort* __restrict__ M,
                                                const int* __restrict__ labels,
                                                int row0,
                                                float* __restrict__ partials) {
    __shared__ u32 s_surv[4][NSURV];
    __shared__ u32 s_seg[4][128];
    __shared__ u32 s_cnt[4];
    __shared__ u32 s_scnt[4];
    int lane = threadIdx.x & 63;
    int wv   = threadIdx.x >> 6;
    int prow = blockIdx.x * 4 + wv;
    int grow = row0 + prow;
    const ushort* rowC = C + (size_t)prow * NROWS;

    if (lane == 0) { s_cnt[wv] = 0; s_scnt[wv] = 0; }
    __syncthreads();

    // segment maxima (mono keys), transposed M: lane holds segs 2*lane, 2*lane+1
    u32 klo = (u32)M[(size_t)(2 * lane)     * NROWS + grow];
    u32 khi = (u32)M[(size_t)(2 * lane + 1) * NROWS + grow];

    // T = largest 16-bit value with count(seg_max >= T) >= KSEL
    u32 T = 0;
    #pragma unroll
    for (int b = 15; b >= 0; --b) {
        u32 cand = T | (1u << b);
        int c = __popcll(__ballot(klo >= cand)) + __popcll(__ballot(khi >= cand));
        if (c >= KSEL) T = cand;
    }

    // survivor-segment id list in LDS (replaces serial ctz chain)
    if (klo >= T) { u32 p = atomicAdd(&s_scnt[wv], 1u); s_seg[wv][p] = 2u * lane; }
    if (khi >= T) { u32 p = atomicAdd(&s_scnt[wv], 1u); s_seg[wv][p] = 2u * lane + 1u; }
    u32 nseg = s_scnt[wv];
    int grp = lane >> 3, sub = lane & 7;   // 8 lanes per segment

    // fast path: up to 32 segments as 4 independent uint4 loads (one mem epoch)
    int  sid[4];
    uint4 vv[4];
    #pragma unroll
    for (int t = 0; t < 4; ++t) {
        u32 ix = (u32)(t * 8 + grp);
        sid[t] = (ix < nseg) ? (int)s_seg[wv][ix] : -1;
    }
    #pragma unroll
    for (int t = 0; t < 4; ++t) {
        if (sid[t] >= 0) vv[t] = *(const uint4*)(rowC + sid[t] * 64 + sub * 8);
    }
    #pragma unroll
    for (int t = 0; t < 4; ++t) {
        if (sid[t] < 0) continue;
        u32 wds[4] = { vv[t].x, vv[t].y, vv[t].z, vv[t].w };
        u32 cbase = (u32)(sid[t] * 64 + sub * 8);
        #pragma unroll
        for (int h = 0; h < 4; ++h) {
            u32 w  = wds[h];
            u32 kA = mono16(w & 0xFFFFu);
            u32 kB = mono16(w >> 16);
            if (kA >= T) { u32 p = atomicAdd(&s_cnt[wv], 1u); if (p < NSURV) s_surv[wv][p] = (kA << 16) | (cbase + 2u * h); }
            if (kB >= T) { u32 p = atomicAdd(&s_cnt[wv], 1u); if (p < NSURV) s_surv[wv][p] = (kB << 16) | (cbase + 2u * h + 1u); }
        }
    }
    // rare tail: nseg > 32
    for (u32 base = 32; base < nseg; base += 8) {
        u32 ix = base + (u32)grp;
        if (ix >= nseg) continue;
        int s = (int)s_seg[wv][ix];
        uint4 v = *(const uint4*)(rowC + s * 64 + sub * 8);
        u32 wds[4] = { v.x, v.y, v.z, v.w };
        u32 cbase = (u32)(s * 64 + sub * 8);
        #pragma unroll
        for (int h = 0; h < 4; ++h) {
            u32 w  = wds[h];
            u32 kA = mono16(w & 0xFFFFu);
            u32 kB = mono16(w >> 16);
            if (kA >= T) { u32 p = atomicAdd(&s_cnt[wv], 1u); if (p < NSURV) s_surv[wv][p] = (kA << 16) | (cbase + 2u * h); }
            if (kB >= T) { u32 p = atomicAdd(&s_cnt[wv], 1u); if (p < NSURV) s_surv[wv][p] = (kB << 16) | (cbase + 2u * h + 1u); }
        }
    }

    u32 cnt = min(s_cnt[wv], (u32)NSURV);     // same-wave LDS: ordered
    int mylab = labels[grow];
    float loss = 0.0f;

    if (cnt <= 64u) {
        // fast path: one survivor per lane; V20 bsearch = 16 ballots
        u32 gg  = ((u32)lane < cnt) ? s_surv[wv][lane] : 0u;
        u32 key = gg >> 16;
        u32 V = 0;
        #pragma unroll
        for (int b = 15; b >= 0; --b) {
            u32 cand = V | (1u << b);
            if (__popcll(__ballot(key >= cand)) >= KSEL) V = cand;
        }
        int cgt  = __popcll(__ballot(key > V));
        int ceq  = __popcll(__ballot(gg != 0 && key == V));
        int need = KSEL - cgt;
        bool incl;
        if (ceq == need) {
            incl = (gg != 0) && (key >= V);
        } else {
            // more ties than slots: take `need` largest cols among ties
            u32 col = gg & 0xFFFFu;
            bool tie = (gg != 0) && (key == V);
            u32 Cv = 0;
            #pragma unroll
            for (int b = 15; b >= 0; --b) {
                u32 cand2 = Cv | (1u << b);
                if (__popcll(__ballot(tie && col >= cand2)) >= need) Cv = cand2;
            }
            incl = (key > V) || (tie && col >= Cv);   // cols unique -> exact
        }
        if (incl) {
            u32 col = gg & 0xFFFFu;
            u32 raw = (key & 0x8000u) ? (key ^ 0x8000u) : (key ^ 0xFFFFu);
            float v = __uint_as_float(raw << 16);
            float p = (v + 1.0f) * 0.5f;
            bool tm = (labels[col] == mylab);
            loss -= tm ? fmaxf(logf(p), -100.0f) : fmaxf(log1pf(-p), -100.0f);
        }
    } else {
        // fallback (rare): 8 survivors per lane
        u32 g[8];
        #pragma unroll
        for (int j = 0; j < 8; ++j) {
            u32 idx = (u32)lane + (u32)j * 64u;
            g[j] = (idx < cnt) ? s_surv[wv][idx] : 0u;
        }
        u32 V = 0;
        #pragma unroll
        for (int b = 15; b >= 0; --b) {
            u32 cand = V | (1u << b);
            int c = 0;
            #pragma unroll
            for (int j = 0; j < 8; ++j)
                c += __popcll(__ballot((g[j] >> 16) >= cand));
            if (c >= KSEL) V = cand;
        }
        int cgt = 0, ceq = 0;
        #pragma unroll
        for (int j = 0; j < 8; ++j) {
            cgt += __popcll(__ballot(g[j] != 0 && (g[j] >> 16) > V));
            ceq += __popcll(__ballot(g[j] != 0 && (g[j] >> 16) == V));
        }
        int need = KSEL - cgt;
        bool all_ties = (ceq == need);
        #pragma unroll
        for (int j = 0; j < 8; ++j) {
            u32 key = g[j] >> 16, col = g[j] & 0xFFFFu;
            if (g[j] != 0 && (key > V || (all_ties && key == V))) {
                u32 raw = (key & 0x8000u) ? (key ^ 0x8000u) : (key ^ 0xFFFFu);
                float v = __uint_as_float(raw << 16);
                float p = (v + 1.0f) * 0.5f;
                bool tm = (labels[col] == mylab);
                loss -= tm ? fmaxf(logf(p), -100.0f) : fmaxf(log1pf(-p), -100.0f);
            }
        }
        if (!all_ties) {
            for (int r = 0; r < need; ++r) {
                u32 best = 0;
                #pragma unroll
                for (int j = 0; j < 8; ++j) {
                    u32 c2 = (g[j] != 0 && (g[j] >> 16) == V) ? ((g[j] & 0xFFFFu) + 1u) : 0u;
                    best = max(best, c2);
                }
                #pragma unroll
                for (int off = 32; off; off >>= 1) best = max(best, (u32)__shfl_xor((int)best, off));
                #pragma unroll
                for (int j = 0; j < 8; ++j) {
                    if (g[j] != 0 && (g[j] >> 16) == V && ((g[j] & 0xFFFFu) + 1u) == best) {
                        u32 col = g[j] & 0xFFFFu;
                        u32 raw = (V & 0x8000u) ? (V ^ 0x8000u) : (V ^ 0xFFFFu);
                        float v = __uint_as_float(raw << 16);
                        float p = (v + 1.0f) * 0.5f;
                        bool tm = (labels[col] == mylab);
                        loss -= tm ? fmaxf(logf(p), -100.0f) : fmaxf(log1pf(-p), -100.0f);
                        g[j] = 0;
                    }
                }
            }
        }
    }

    #pragma unroll
    for (int off = 32; off; off >>= 1) loss += __shfl_xor(loss, off);
    if (lane == 0) partials[grow] = loss;
}

__global__ __launch_bounds__(256) void k_final(const float* __restrict__ partials,
                                               float* __restrict__ out) {
    __shared__ float s[4];
    int tid = threadIdx.x, lane = tid & 63, wvi = tid >> 6;
    const float4* p4 = (const float4*)partials;
    float sum = 0.0f;
    #pragma unroll
    for (int i = 0; i < 8; ++i) {
        float4 v = p4[tid + i * 256];
        sum += v.x + v.y + v.z + v.w;
    }
    #pragma unroll
    for (int off = 32; off; off >>= 1) sum += __shfl_xor(sum, off);
    if (lane == 0) s[wvi] = sum;
    __syncthreads();
    if (tid == 0) out[0] = (s[0] + s[1] + s[2] + s[3]) * (1.0f / (float)(NROWS * KSEL));
}

extern "C" void kernel_launch(void* const* d_in, const int* in_sizes, int n_in,
                              void* d_out, int out_size, void* d_ws, size_t ws_size,
                              hipStream_t stream) {
    const float* batch  = (const float*)d_in[0];
    const int*   labels = (const int*)d_in[1];

    ushort* xn = (ushort*)d_ws;
    ushort* C  = xn + (size_t)NROWS * DIM;
    // M (2 MB, transposed seg-major) and partials (32 KB) live in the batch
    // input buffer (16 MB): batch is fully consumed by k_norm first.
    ushort* M        = (ushort*)d_in[0];
    float*  partials = (float*)((char*)d_in[0] + (4u << 20));

    size_t need_full = (size_t)NROWS * DIM * 2 + (size_t)NROWS * NROWS * 2;

    k_norm<<<NROWS / 4, 256, 0, stream>>>(batch, xn);

    if (ws_size >= need_full) {
        // full symmetric path: 2080 lower-triangle blocks, one select pass
        k_gemm<true><<<dim3(64 * 65 / 2), 256, 0, stream>>>(xn, C, M, 0);
        k_select<<<NROWS / 4, 256, 0, stream>>>(C, M, labels, 0, partials);
    } else {
        // fallback: panel path (24 MB of ws)
        for (int p = 0; p < NROWS / PANEL; ++p) {
            k_gemm<false><<<dim3(64, PANEL / 128), 256, 0, stream>>>(xn, C, M, p * PANEL);
            k_select<<<PANEL / 4, 256, 0, stream>>>(C, M, labels, p * PANEL, partials);
        }
    }
    k_final<<<1, 256, 0, stream>>>(partials, (float*)d_out);
}